// Round 1
// baseline (2395.681 us; speedup 1.0000x reference)
//
#include <hip/hip_runtime.h>
#include <math.h>

// Problem constants
#define TN 4096            // T (FFT length)
#define NTHREADS 256
#define ELEMS 16           // TN / NTHREADS
#define CT 262144          // C*T (GEMM K)
#define FEAT 512           // N
#define M_ROWS 320         // 5 views * 64 batch
#define VSTR 16777216ull   // floats per view buffer (64*262144)

// ws layout (floats):
//   [0)                 views: 4 * VSTR           (compressed, distorted, noisy, combined)
//   [4*VSTR)            F:     320*512
//   [.. +163840)        fn:    320*512
//   [.. +163840)        acc:   4 floats (cons, adj_sim, lse_sum, unused)
// total ~258 MB

__device__ __forceinline__ float block_reduce_sum(float v, float* red) {
  int tid = threadIdx.x;
  red[tid] = v;
  __syncthreads();
  #pragma unroll
  for (int s = 128; s > 0; s >>= 1) {
    if (tid < s) red[tid] += red[tid + s];
    __syncthreads();
  }
  float r = red[0];
  __syncthreads();
  return r;
}

// Forward radix-2 DIF: natural input -> bit-reversed spectrum. exp(-2pi i nk/N).
__device__ void fft_dif_forward(float* re, float* im) {
  int tid = threadIdx.x;
  for (int m = TN; m >= 2; m >>= 1) {
    int half = m >> 1;
    float w = -6.2831853071795864769f / (float)m;
    for (int q = tid; q < TN / 2; q += NTHREADS) {
      int j = q & (half - 1);
      int i0 = 2 * q - j;
      int i1 = i0 + half;
      float ur = re[i0], ui = im[i0];
      float vr = re[i1], vi = im[i1];
      re[i0] = ur + vr; im[i0] = ui + vi;
      float dr = ur - vr, di = ui - vi;
      float s, c;
      __sincosf(w * (float)j, &s, &c);
      re[i1] = dr * c - di * s;
      im[i1] = dr * s + di * c;
    }
    __syncthreads();
  }
}

// Inverse radix-2 DIT: bit-reversed input -> natural output (unscaled; caller divides by N).
__device__ void fft_dit_inverse(float* re, float* im) {
  int tid = threadIdx.x;
  for (int m = 2; m <= TN; m <<= 1) {
    int half = m >> 1;
    float w = 6.2831853071795864769f / (float)m;
    for (int q = tid; q < TN / 2; q += NTHREADS) {
      int j = q & (half - 1);
      int i0 = 2 * q - j;
      int i1 = i0 + half;
      float s, c;
      __sincosf(w * (float)j, &s, &c);
      float xr = re[i1], xi = im[i1];
      float tr = xr * c - xi * s;
      float ti = xr * s + xi * c;
      float ur = re[i0], ui = im[i0];
      re[i0] = ur + tr; im[i0] = ui + ti;
      re[i1] = ur - tr; im[i1] = ui - ti;
    }
    __syncthreads();
  }
}

__device__ __forceinline__ float fmask_val(int k, int fs, int fw) {
  return (k >= fs && k < fs + fw) ? 0.1f : 1.0f;
}
__device__ __forceinline__ float gmask(int k, int fs, int fw) {
  int km = (TN - k) & (TN - 1);
  return 0.5f * (fmask_val(k, fs, fw) + fmask_val(km, fs, fw));
}
__device__ __forceinline__ float wmask(int k, int cutoff) {
  int km = (TN - k) & (TN - 1);
  return 0.5f * ((k < cutoff ? 1.0f : 0.0f) + (km < cutoff ? 1.0f : 0.0f));
}

__global__ __launch_bounds__(NTHREADS)
void views_kernel(const float* __restrict__ x,
                  const float* __restrict__ noise1,
                  const float* __restrict__ noise2,
                  const int* __restrict__ fs_p,
                  const int* __restrict__ ts_p,
                  float* __restrict__ views) {
  __shared__ float sre[TN];
  __shared__ float sIm[TN];
  __shared__ float red[NTHREADS];

  const int tid = threadIdx.x;
  const int row = blockIdx.x;            // b*64 + c, 0..4095
  const int fs = *fs_p;
  const int ts = *ts_p;
  const int fw = 409;                    // int(0.1*4096)
  const size_t base = (size_t)row * TN;
  const float invN = 1.0f / (float)TN;

  // load x row into registers
  float xr[ELEMS];
  #pragma unroll
  for (int j = 0; j < ELEMS; ++j) xr[j] = x[base + tid + NTHREADS * j];

  // std of x (ddof=1)
  float s1 = 0.f, s2 = 0.f;
  #pragma unroll
  for (int j = 0; j < ELEMS; ++j) { s1 += xr[j]; s2 += xr[j] * xr[j]; }
  s1 = block_reduce_sum(s1, red);
  s2 = block_reduce_sum(s2, red);
  float std_x = sqrtf(fmaxf(0.f, (s2 - s1 * s1 * invN) / (float)(TN - 1)));

  // view 2: noisy = x + noise1 * 0.02 * std_x
  {
    float a = 0.02f * std_x;
    #pragma unroll
    for (int j = 0; j < ELEMS; ++j) {
      int idx = tid + NTHREADS * j;
      views[2ull * VSTR + base + idx] = xr[j] + noise1[base + idx] * a;
    }
  }

  // forward FFT of x row
  #pragma unroll
  for (int j = 0; j < ELEMS; ++j) {
    int idx = tid + NTHREADS * j;
    sre[idx] = xr[j];
    sIm[idx] = 0.f;
  }
  __syncthreads();
  fft_dif_forward(sre, sIm);

  // park spectrum (bit-reversed storage) in registers
  float spr[ELEMS], spi[ELEMS];
  #pragma unroll
  for (int j = 0; j < ELEMS; ++j) {
    int idx = tid + NTHREADS * j;
    spr[j] = sre[idx];
    spi[j] = sIm[idx];
  }

  // ---- view 0: compressed (cutoff 2048) ----
  #pragma unroll
  for (int j = 0; j < ELEMS; ++j) {
    int idx = tid + NTHREADS * j;
    int k = (int)(__brev((unsigned)idx) >> 20);
    float mv = wmask(k, 2048);
    sre[idx] = spr[j] * mv;
    sIm[idx] = spi[j] * mv;
  }
  __syncthreads();
  fft_dit_inverse(sre, sIm);
  #pragma unroll
  for (int j = 0; j < ELEMS; ++j) {
    int idx = tid + NTHREADS * j;
    views[base + idx] = sre[idx] * invN;
  }

  // ---- view 1: distorted (freq mask symmetrized, then time mask) ----
  #pragma unroll
  for (int j = 0; j < ELEMS; ++j) {
    int idx = tid + NTHREADS * j;
    int k = (int)(__brev((unsigned)idx) >> 20);
    float mv = gmask(k, fs, fw);
    sre[idx] = spr[j] * mv;
    sIm[idx] = spi[j] * mv;
  }
  __syncthreads();
  fft_dit_inverse(sre, sIm);
  #pragma unroll
  for (int j = 0; j < ELEMS; ++j) {
    int idx = tid + NTHREADS * j;
    float tm = (idx >= ts && idx < ts + 204) ? 0.1f : 1.0f;
    views[1ull * VSTR + base + idx] = sre[idx] * invN * tm;
  }

  // ---- view 3: combined = add_noise(distort(compress(x,0.25))) ----
  #pragma unroll
  for (int j = 0; j < ELEMS; ++j) {
    int idx = tid + NTHREADS * j;
    int k = (int)(__brev((unsigned)idx) >> 20);
    float mv = wmask(k, 3072) * gmask(k, fs, fw);
    sre[idx] = spr[j] * mv;
    sIm[idx] = spi[j] * mv;
  }
  __syncthreads();
  fft_dit_inverse(sre, sIm);
  float zr[ELEMS];
  s1 = 0.f; s2 = 0.f;
  #pragma unroll
  for (int j = 0; j < ELEMS; ++j) {
    int idx = tid + NTHREADS * j;
    float tm = (idx >= ts && idx < ts + 204) ? 0.1f : 1.0f;
    float z = sre[idx] * invN * tm;
    zr[j] = z;
    s1 += z;
    s2 += z * z;
  }
  s1 = block_reduce_sum(s1, red);
  s2 = block_reduce_sum(s2, red);
  float std_z = sqrtf(fmaxf(0.f, (s2 - s1 * s1 * invN) / (float)(TN - 1)));
  {
    float a = 0.02f * std_z;
    #pragma unroll
    for (int j = 0; j < ELEMS; ++j) {
      int idx = tid + NTHREADS * j;
      views[3ull * VSTR + base + idx] = zr[j] + noise2[base + idx] * a;
    }
  }
}

__global__ __launch_bounds__(NTHREADS)
void init_feats_kernel(const float* __restrict__ bv, float* __restrict__ F) {
  int i = blockIdx.x * NTHREADS + threadIdx.x;
  if (i < M_ROWS * FEAT) F[i] = bv[i & (FEAT - 1)];
}

// fp32 GEMM: C[320,512] += A[320,262144] @ W[262144,512]; split-K with atomics.
#define BM 64
#define BN 64
#define BK 32
#define KSPLIT 32
#define KCHUNK (CT / KSPLIT)   // 8192

__global__ __launch_bounds__(NTHREADS)
void gemm_kernel(const float* __restrict__ x,
                 const float* __restrict__ views,
                 const float* __restrict__ W,
                 float* __restrict__ F) {
  __shared__ __align__(16) float As[BK][68];
  __shared__ __align__(16) float Ws[BK][68];
  __shared__ const float* Arow[BM];

  const int tid = threadIdx.x;
  const int n0 = blockIdx.x * BN;
  const int m0 = blockIdx.y * BM;
  const size_t k0 = (size_t)blockIdx.z * KCHUNK;

  if (tid < BM) {
    int m = m0 + tid;
    int v = m >> 6, b = m & 63;
    Arow[tid] = (v == 0) ? (x + (size_t)b * CT)
                         : (views + (size_t)(v - 1) * VSTR + (size_t)b * CT);
  }
  __syncthreads();

  const int tx = tid & 15;   // n quad
  const int ty = tid >> 4;   // m quad
  float acc[4][4] = {{0.f}};

  const int lkA = tid & 31, lrA = tid >> 5;      // A staging
  const int ln4 = tid & 15, lkW = tid >> 4;      // W staging

  for (int kk = 0; kk < KCHUNK; kk += BK) {
    #pragma unroll
    for (int p = 0; p < 8; ++p) {
      int r = lrA + p * 8;
      As[lkA][r] = Arow[r][k0 + kk + lkA];
    }
    #pragma unroll
    for (int p = 0; p < 2; ++p) {
      int kr = lkW + p * 16;
      const float4 w4 = *(const float4*)&W[(k0 + kk + kr) * FEAT + n0 + ln4 * 4];
      *(float4*)&Ws[kr][ln4 * 4] = w4;
    }
    __syncthreads();
    #pragma unroll
    for (int k = 0; k < BK; ++k) {
      float4 a4 = *(const float4*)&As[k][ty * 4];
      float4 w4 = *(const float4*)&Ws[k][tx * 4];
      float a[4] = {a4.x, a4.y, a4.z, a4.w};
      float w[4] = {w4.x, w4.y, w4.z, w4.w};
      #pragma unroll
      for (int i = 0; i < 4; ++i)
        #pragma unroll
        for (int j = 0; j < 4; ++j)
          acc[i][j] += a[i] * w[j];
    }
    __syncthreads();
  }

  #pragma unroll
  for (int i = 0; i < 4; ++i)
    #pragma unroll
    for (int j = 0; j < 4; ++j)
      atomicAdd(&F[(size_t)(m0 + ty * 4 + i) * FEAT + n0 + tx * 4 + j], acc[i][j]);
}

__global__ __launch_bounds__(NTHREADS)
void norm_cons_kernel(const float* __restrict__ F, float* __restrict__ fn,
                      float* __restrict__ acc) {
  __shared__ float red[NTHREADS];
  const int i = blockIdx.x;          // 0..319
  const int tid = threadIdx.x;
  const float* Fr = F + (size_t)i * FEAT;
  float v0 = Fr[tid], v1 = Fr[tid + 256];
  float ss = block_reduce_sum(v0 * v0 + v1 * v1, red);
  float inv = rsqrtf(ss);
  fn[(size_t)i * FEAT + tid] = v0 * inv;
  fn[(size_t)i * FEAT + tid + 256] = v1 * inv;
  if (i >= 64) {
    const float* F0 = F + (size_t)(i & 63) * FEAT;
    float d0 = v0 - F0[tid], d1 = v1 - F0[tid + 256];
    float ds = block_reduce_sum(d0 * d0 + d1 * d1, red);
    if (tid == 0) atomicAdd(&acc[0], ds);
  }
}

__global__ __launch_bounds__(NTHREADS)
void sim_kernel(const float* __restrict__ fn, float* __restrict__ acc) {
  __shared__ float frow[FEAT];
  __shared__ float red[NTHREADS];
  const int i = blockIdx.x;          // 0..319
  const int tid = threadIdx.x;
  frow[tid] = fn[(size_t)i * FEAT + tid];
  frow[tid + 256] = fn[(size_t)i * FEAT + tid + 256];
  __syncthreads();

  float sv[2] = {-1e30f, -1e30f};
  #pragma unroll
  for (int p = 0; p < 2; ++p) {
    int j = tid + p * 256;
    if (j < M_ROWS) {
      const float* g = fn + (size_t)j * FEAT;
      float d = 0.f;
      for (int t = 0; t < FEAT; ++t) d += frow[t] * g[t];
      sv[p] = d * 10.0f;   // / TEMPERATURE
    }
  }
  // row max
  red[tid] = fmaxf(sv[0], sv[1]);
  __syncthreads();
  #pragma unroll
  for (int s = 128; s > 0; s >>= 1) {
    if (tid < s) red[tid] = fmaxf(red[tid], red[tid + s]);
    __syncthreads();
  }
  float mx = red[0];
  __syncthreads();
  float es = 0.f;
  #pragma unroll
  for (int p = 0; p < 2; ++p) {
    int j = tid + p * 256;
    if (j < M_ROWS) es += expf(sv[p] - mx);
  }
  es = block_reduce_sum(es, red);
  float lse = mx + logf(es);

  #pragma unroll
  for (int p = 0; p < 2; ++p) {
    int j = tid + p * 256;
    if (j < M_ROWS && (j == i - 1 || j == i + 1)) atomicAdd(&acc[1], sv[p]);
  }
  if (tid == 0) {
    float mult = (i > 0 ? 1.f : 0.f) + (i < M_ROWS - 1 ? 1.f : 0.f);
    atomicAdd(&acc[2], mult * lse);
  }
}

__global__ void final_kernel(const float* __restrict__ acc, float* __restrict__ out) {
  if (threadIdx.x == 0 && blockIdx.x == 0) {
    float cons = acc[0] * (1.0f / (4.0f * 64.0f * 512.0f));
    float contr = (acc[2] - acc[1]) * (1.0f / 638.0f);  // -(adj - lse)/638
    out[0] = cons + 0.5f * contr;
  }
}

extern "C" void kernel_launch(void* const* d_in, const int* in_sizes, int n_in,
                              void* d_out, int out_size, void* d_ws, size_t ws_size,
                              hipStream_t stream) {
  const float* x  = (const float*)d_in[0];
  const float* W  = (const float*)d_in[1];
  const float* bv = (const float*)d_in[2];
  const float* n1 = (const float*)d_in[3];
  const float* n2 = (const float*)d_in[4];
  const int* fs   = (const int*)d_in[5];
  const int* ts   = (const int*)d_in[6];
  float* out = (float*)d_out;

  float* views = (float*)d_ws;
  float* F     = views + 4ull * VSTR;
  float* fn    = F + (size_t)M_ROWS * FEAT;
  float* acc   = fn + (size_t)M_ROWS * FEAT;

  hipMemsetAsync(acc, 0, 4 * sizeof(float), stream);
  views_kernel<<<4096, NTHREADS, 0, stream>>>(x, n1, n2, fs, ts, views);
  init_feats_kernel<<<(M_ROWS * FEAT + NTHREADS - 1) / NTHREADS, NTHREADS, 0, stream>>>(bv, F);
  gemm_kernel<<<dim3(FEAT / BN, M_ROWS / BM, KSPLIT), NTHREADS, 0, stream>>>(x, views, W, F);
  norm_cons_kernel<<<M_ROWS, NTHREADS, 0, stream>>>(F, fn, acc);
  sim_kernel<<<M_ROWS, NTHREADS, 0, stream>>>(fn, acc);
  final_kernel<<<1, 64, 0, stream>>>(acc, out);
}